// Round 1
// baseline (1005.942 us; speedup 1.0000x reference)
//
#include <hip/hip_runtime.h>
#include <math.h>

#define NEG_SLOPE 0.2f

__device__ __forceinline__ float mishf(float x) {
    float sp = (x > 20.f) ? x : log1pf(expf(x));
    return x * tanhf(sp);
}

// ---- Layer-1 node GEMM: hpre1 = x @ W1 [N,16]; alpha_src/dst per head [N,8 packed]
__global__ void gemm1_kernel(const float* __restrict__ x, const float* __restrict__ W1,
                             const float* __restrict__ a_src, const float* __restrict__ a_dst,
                             float* __restrict__ hpre, float* __restrict__ asad, int N) {
    __shared__ float Wl[128 * 16];
    __shared__ float xs[16 * 132];   // +4 pad breaks 16-way bank conflict
    int tid = threadIdx.x;
    for (int i = tid; i < 2048; i += 256) Wl[i] = W1[i];
    int nodebase = blockIdx.x * 16;
    const float4* x4 = (const float4*)(x + (size_t)nodebase * 128);
    for (int i = tid; i < 512; i += 256) {
        float4 v = x4[i];
        int e = i * 4;
        int nl = e >> 7, k = e & 127;
        float* dp = &xs[nl * 132 + k];
        dp[0] = v.x; dp[1] = v.y; dp[2] = v.z; dp[3] = v.w;
    }
    __syncthreads();
    int nl = tid >> 4, ch = tid & 15;
    const float* xr = &xs[nl * 132];
    float acc = 0.f;
    #pragma unroll 8
    for (int k = 0; k < 128; k++) acc += xr[k] * Wl[k * 16 + ch];
    int node = nodebase + nl;
    if (node < N) {
        hpre[(size_t)node * 16 + ch] = acc;
        float ps = acc * a_src[ch];
        float pd = acc * a_dst[ch];
        ps += __shfl_xor(ps, 1); ps += __shfl_xor(ps, 2);
        pd += __shfl_xor(pd, 1); pd += __shfl_xor(pd, 2);
        if ((ch & 3) == 0) {
            int head = ch >> 2;
            asad[(size_t)node * 8 + head] = ps;
            asad[(size_t)node * 8 + 4 + head] = pd;
        }
    }
}

// ---- Layer-2 node GEMM: hpre2 = hpost1 @ W2 [N,32]; alpha scalars [N,2 packed]
__global__ void gemm2_kernel(const float* __restrict__ hpost1, const float* __restrict__ W2,
                             const float* __restrict__ a_src, const float* __restrict__ a_dst,
                             float* __restrict__ hpre2, float* __restrict__ asad2, int N) {
    __shared__ float Wl[16 * 32];
    __shared__ float hs[8 * 20];
    int tid = threadIdx.x;
    for (int i = tid; i < 512; i += 256) Wl[i] = W2[i];
    int nodebase = blockIdx.x * 8;
    const float4* h4 = (const float4*)(hpost1 + (size_t)nodebase * 16);
    if (tid < 32) {
        float4 v = h4[tid];
        int e = tid * 4;
        int nl = e >> 4, k = e & 15;
        float* dp = &hs[nl * 20 + k];
        dp[0] = v.x; dp[1] = v.y; dp[2] = v.z; dp[3] = v.w;
    }
    __syncthreads();
    int nl = tid >> 5, ch = tid & 31;
    const float* hr = &hs[nl * 20];
    float acc = 0.f;
    #pragma unroll
    for (int k = 0; k < 16; k++) acc += hr[k] * Wl[k * 32 + ch];
    int node = nodebase + nl;
    if (node < N) {
        hpre2[(size_t)node * 32 + ch] = acc;
        float ps = acc * a_src[ch];
        float pd = acc * a_dst[ch];
        #pragma unroll
        for (int m = 1; m < 32; m <<= 1) { ps += __shfl_xor(ps, m); pd += __shfl_xor(pd, m); }
        if (ch == 0) {
            asad2[(size_t)node * 2] = ps;
            asad2[(size_t)node * 2 + 1] = pd;
        }
    }
}

// ---- CSR build: histogram of dst (incl. self-loops appended at end)
__global__ void hist_kernel(const int* __restrict__ dst, int E, int Etot, int* __restrict__ deg) {
    int i = blockIdx.x * blockDim.x + threadIdx.x;
    if (i >= Etot) return;
    int d = (i < E) ? dst[i] : (i - E);
    atomicAdd(&deg[d], 1);
}

__global__ void scan1_kernel(const int* __restrict__ deg, int N, int* __restrict__ incl, int* __restrict__ bsum) {
    __shared__ int s[256];
    int t = threadIdx.x;
    int i = blockIdx.x * 256 + t;
    s[t] = (i < N) ? deg[i] : 0;
    __syncthreads();
    for (int off = 1; off < 256; off <<= 1) {
        int tmp = (t >= off) ? s[t - off] : 0;
        __syncthreads();
        s[t] += tmp;
        __syncthreads();
    }
    if (i < N) incl[i] = s[t];
    if (t == 255) bsum[blockIdx.x] = s[255];
}

__global__ void scan2_kernel(int* __restrict__ bsum, int nb) {
    __shared__ int s[512];
    int t = threadIdx.x;
    s[t] = (t < nb) ? bsum[t] : 0;
    __syncthreads();
    for (int off = 1; off < 512; off <<= 1) {
        int tmp = (t >= off) ? s[t - off] : 0;
        __syncthreads();
        s[t] += tmp;
        __syncthreads();
    }
    if (t < nb) bsum[t] = s[t];
}

__global__ void scan3_kernel(const int* __restrict__ deg, const int* __restrict__ incl,
                             const int* __restrict__ bsum, int N,
                             int* __restrict__ row_start, int* __restrict__ cursor) {
    int i = blockIdx.x * 256 + threadIdx.x;
    if (i >= N) return;
    int off = (blockIdx.x > 0) ? bsum[blockIdx.x - 1] : 0;
    int ex = incl[i] - deg[i] + off;
    row_start[i] = ex;
    cursor[i] = ex;
    if (i == N - 1) row_start[N] = ex + deg[i];
}

__global__ void scat_kernel(const int* __restrict__ src, const int* __restrict__ dst, int E, int Etot,
                            int* __restrict__ cursor, int* __restrict__ ssorted) {
    int i = blockIdx.x * blockDim.x + threadIdx.x;
    if (i >= Etot) return;
    int s, d;
    if (i < E) { s = src[i]; d = dst[i]; } else { s = d = i - E; }
    int pos = atomicAdd(&cursor[d], 1);
    ssorted[pos] = s;
}

// ---- Fused edge softmax + aggregate, layer 1 (H=4, C=4). One wave per node.
// Lanes: 4 edge-rows x 16 channels. Two passes: max, then exp/sum/accumulate.
__global__ void agg1_kernel(const int* __restrict__ row_start, const int* __restrict__ ssorted,
                            const float* __restrict__ asad, const float* __restrict__ hpre,
                            const float* __restrict__ b1, float* __restrict__ hpost, int N) {
    int wave = threadIdx.x >> 6;
    int lane = threadIdx.x & 63;
    int node = blockIdx.x * 4 + wave;
    if (node >= N) return;
    int start = row_start[node], end = row_start[node + 1];
    int er = lane >> 4, ch = lane & 15, head = ch >> 2;
    float adh = asad[(size_t)node * 8 + 4 + head];
    float m = -INFINITY;
    for (int j = start + er; j < end; j += 4) {
        int s = ssorted[j];
        float e = asad[(size_t)s * 8 + head] + adh;
        e = (e > 0.f) ? e : NEG_SLOPE * e;
        m = fmaxf(m, e);
    }
    m = fmaxf(m, __shfl_xor(m, 16));
    m = fmaxf(m, __shfl_xor(m, 32));
    float den = 0.f, acc = 0.f;
    for (int j = start + er; j < end; j += 4) {
        int s = ssorted[j];
        float e = asad[(size_t)s * 8 + head] + adh;
        e = (e > 0.f) ? e : NEG_SLOPE * e;
        float ee = expf(e - m);
        den += ee;
        acc += hpre[(size_t)s * 16 + ch] * ee;
    }
    den += __shfl_xor(den, 16);
    den += __shfl_xor(den, 32);
    acc += __shfl_xor(acc, 16);
    acc += __shfl_xor(acc, 32);
    if (er == 0) {
        float v = acc / (den + 1e-16f) + b1[ch];
        hpost[(size_t)node * 16 + ch] = mishf(v);
    }
}

// ---- Fused edge softmax + aggregate, layer 2 (H=1, C=32). 2 edge-rows x 32 ch.
__global__ void agg2_kernel(const int* __restrict__ row_start, const int* __restrict__ ssorted,
                            const float* __restrict__ asad2, const float* __restrict__ hpre2,
                            const float* __restrict__ b2, float* __restrict__ hpost2, int N) {
    int wave = threadIdx.x >> 6;
    int lane = threadIdx.x & 63;
    int node = blockIdx.x * 4 + wave;
    if (node >= N) return;
    int start = row_start[node], end = row_start[node + 1];
    int er = lane >> 5, ch = lane & 31;
    float adh = asad2[(size_t)node * 2 + 1];
    float m = -INFINITY;
    for (int j = start + er; j < end; j += 2) {
        int s = ssorted[j];
        float e = asad2[(size_t)s * 2] + adh;
        e = (e > 0.f) ? e : NEG_SLOPE * e;
        m = fmaxf(m, e);
    }
    m = fmaxf(m, __shfl_xor(m, 32));
    float den = 0.f, acc = 0.f;
    for (int j = start + er; j < end; j += 2) {
        int s = ssorted[j];
        float e = asad2[(size_t)s * 2] + adh;
        e = (e > 0.f) ? e : NEG_SLOPE * e;
        float ee = expf(e - m);
        den += ee;
        acc += hpre2[(size_t)s * 32 + ch] * ee;
    }
    den += __shfl_xor(den, 32);
    acc += __shfl_xor(acc, 32);
    if (er == 0) {
        float v = acc / (den + 1e-16f) + b2[ch];
        hpost2[(size_t)node * 32 + ch] = mishf(v);
    }
}

// ---- Mean pool: batch is sorted, so run-length accumulate + rare atomics.
__global__ void pool_kernel(const float* __restrict__ hpost2, const int* __restrict__ batch,
                            int N, float* __restrict__ pool, float* __restrict__ cnt) {
    int tid = threadIdx.x;
    int r = tid >> 5, ch = tid & 31;
    int base = blockIdx.x * 512;
    int cur = -1;
    float sum = 0.f, c = 0.f;
    for (int it = 0; it < 64; it++) {
        int n = base + it * 8 + r;
        if (n >= N) break;
        int g = batch[n];
        if (g != cur) {
            if (cur >= 0) {
                atomicAdd(&pool[cur * 32 + ch], sum);
                if (ch == 0) atomicAdd(&cnt[cur], c);
            }
            cur = g; sum = 0.f; c = 0.f;
        }
        sum += hpost2[(size_t)n * 32 + ch];
        c += 1.f;
    }
    if (cur >= 0) {
        atomicAdd(&pool[cur * 32 + ch], sum);
        if (ch == 0) atomicAdd(&cnt[cur], c);
    }
}

__global__ void fin_kernel(const float* __restrict__ pool, const float* __restrict__ cnt,
                           float* __restrict__ out, int NG) {
    int i = blockIdx.x * blockDim.x + threadIdx.x;
    if (i >= NG * 32) return;
    out[i] = pool[i] / fmaxf(cnt[i >> 5], 1.0f);
}

extern "C" void kernel_launch(void* const* d_in, const int* in_sizes, int n_in,
                              void* d_out, int out_size, void* d_ws, size_t ws_size,
                              hipStream_t stream) {
    const float* x   = (const float*)d_in[0];
    const int* eidx  = (const int*)d_in[1];
    const int* batch = (const int*)d_in[2];
    const float* W1  = (const float*)d_in[3];
    const float* b1  = (const float*)d_in[4];
    const float* as1 = (const float*)d_in[5];
    const float* ad1 = (const float*)d_in[6];
    const float* W2  = (const float*)d_in[7];
    const float* b2  = (const float*)d_in[8];
    const float* as2 = (const float*)d_in[9];
    const float* ad2 = (const float*)d_in[10];
    float* out = (float*)d_out;

    int N = in_sizes[0] / 128;
    int E = in_sizes[1] / 2;
    int Etot = E + N;
    int NG = out_size / 32;
    const int* esrc = eidx;
    const int* edst = eidx + E;

    char* p = (char*)d_ws;
    auto alloc = [&](size_t elems) { void* r = (void*)p; p += elems * 4; return r; };
    int* deg       = (int*)alloc(N);
    int* row_start = (int*)alloc(N + 1);
    int* cursor    = (int*)alloc(N);
    int* incl      = (int*)alloc(N);
    int* bsum      = (int*)alloc(512);
    int* ssorted   = (int*)alloc(Etot);
    float* hpre1   = (float*)alloc((size_t)N * 16);
    float* asad1   = (float*)alloc((size_t)N * 8);
    float* hpost1  = (float*)alloc((size_t)N * 16);
    float* hpre2   = (float*)alloc((size_t)N * 32);
    float* asad2p  = (float*)alloc((size_t)N * 2);
    float* hpost2  = (float*)alloc((size_t)N * 32);
    float* pool    = (float*)alloc((size_t)NG * 32);
    float* cnt     = (float*)alloc(NG);

    hipMemsetAsync(deg, 0, (size_t)N * 4, stream);
    hipMemsetAsync(pool, 0, (size_t)NG * 32 * 4, stream);
    hipMemsetAsync(cnt, 0, (size_t)NG * 4, stream);

    int nb_scan = (N + 255) / 256;
    hist_kernel<<<(Etot + 255) / 256, 256, 0, stream>>>(edst, E, Etot, deg);
    gemm1_kernel<<<(N + 15) / 16, 256, 0, stream>>>(x, W1, as1, ad1, hpre1, asad1, N);
    scan1_kernel<<<nb_scan, 256, 0, stream>>>(deg, N, incl, bsum);
    scan2_kernel<<<1, 512, 0, stream>>>(bsum, nb_scan);
    scan3_kernel<<<nb_scan, 256, 0, stream>>>(deg, incl, bsum, N, row_start, cursor);
    scat_kernel<<<(Etot + 255) / 256, 256, 0, stream>>>(esrc, edst, E, Etot, cursor, ssorted);
    agg1_kernel<<<(N + 3) / 4, 256, 0, stream>>>(row_start, ssorted, asad1, hpre1, b1, hpost1, N);
    gemm2_kernel<<<(N + 7) / 8, 256, 0, stream>>>(hpost1, W2, as2, ad2, hpre2, asad2p, N);
    agg2_kernel<<<(N + 3) / 4, 256, 0, stream>>>(row_start, ssorted, asad2p, hpre2, b2, hpost2, N);
    pool_kernel<<<(N + 511) / 512, 256, 0, stream>>>(hpost2, batch, N, pool, cnt);
    fin_kernel<<<(NG * 32 + 255) / 256, 256, 0, stream>>>(pool, cnt, out, NG);
}